// Round 5
// baseline (499.620 us; speedup 1.0000x reference)
//
#include <hip/hip_runtime.h>

#define D 1024
#define NB1 48
#define NB2 48
#define RR 36
#define LL 30
#define NH 4

typedef short bf16x8 __attribute__((ext_vector_type(8)));
typedef float f32x4 __attribute__((ext_vector_type(4)));
typedef unsigned short u16x8 __attribute__((ext_vector_type(8)));
typedef unsigned short ush;

#define MFMA16(a, b, c) __builtin_amdgcn_mfma_f32_16x16x32_bf16(a, b, c, 0, 0, 0)

__device__ __forceinline__ ush f2bf(float x) {
  unsigned u = __float_as_uint(x);
  u += 0x7FFF + ((u >> 16) & 1);
  return (ush)(u >> 16);
}
__device__ __forceinline__ float bf2f(ush h) {
  return __uint_as_float(((unsigned)h) << 16);
}
__device__ __forceinline__ void split8(const float* v, bf16x8& h8, bf16x8& l8) {
  u16x8 hi, lo;
#pragma unroll
  for (int i = 0; i < 8; ++i) {
    ush h = f2bf(v[i]);
    hi[i] = h;
    lo[i] = f2bf(v[i] - bf2f(h));
  }
  h8 = __builtin_bit_cast(bf16x8, hi);
  l8 = __builtin_bit_cast(bf16x8, lo);
}

// ---- fp32 row-major (rows x 1024) -> split-bf16 MFMA fragment layout ----
__device__ __forceinline__ void conv_body(const float* __restrict__ X,
                                          ush* __restrict__ out,
                                          int rows, int g) {
  const int lane = threadIdx.x & 63;
  const int tile = g >> 5, kc = g & 31;
  const int row = tile * 16 + (lane & 15);
  const int k = kc * 32 + (lane >> 4) * 8;
  float v[8];
  if (row < rows) {
    const float4* s = (const float4*)(X + (size_t)row * 1024 + k);
    float4 x0 = s[0], x1 = s[1];
    v[0] = x0.x; v[1] = x0.y; v[2] = x0.z; v[3] = x0.w;
    v[4] = x1.x; v[5] = x1.y; v[6] = x1.z; v[7] = x1.w;
  } else {
#pragma unroll
    for (int i = 0; i < 8; ++i) v[i] = 0.f;
  }
  bf16x8 hi, lo;
  split8(v, hi, lo);
  bf16x8* o = (bf16x8*)(out + (size_t)g * 1024 + lane * 8);
  o[0] = hi;
  o[64] = lo;
}

// 6 input matrices in one launch. grid (864, 6)
__global__ __launch_bounds__(256) void conv6(
    const float* __restrict__ v1, const float* __restrict__ v2,
    const float* __restrict__ wimg, const float* __restrict__ wtxt,
    const float* __restrict__ w1a, const float* __restrict__ w1b,
    ush* v1f, ush* v2f, ush* wimgf, ush* wtxtf, ush* w1af, ush* w1bf) {
  const float* X; ush* O; int rows;
  switch (blockIdx.y) {
    case 0: X = v1; O = v1f; rows = 1728; break;
    case 1: X = v2; O = v2f; rows = 1440; break;
    case 2: X = wimg; O = wimgf; rows = 1024; break;
    case 3: X = wtxt; O = wtxtf; rows = 1024; break;
    case 4: X = w1a; O = w1af; rows = 1024; break;
    default: X = w1b; O = w1bf; rows = 1024; break;
  }
  const int tiles = (rows + 15) >> 4;
  const int g = blockIdx.x * 4 + (threadIdx.x >> 6);
  if (g >= tiles * 32) return;
  conv_body(X, O, rows, g);
}

// merged: conv k1,k2 + convG. 1D grid 3264 blocks.
__global__ __launch_bounds__(256) void conv_post(
    const float* __restrict__ k1, const float* __restrict__ k2,
    const float* __restrict__ G2a, const float* __restrict__ G1b,
    ush* k1f, ush* k2f, ush* G2aF, ush* G1bF) {
  const int bid = blockIdx.x;
  const int t = threadIdx.x, lane = t & 63;
  if (bid < 1728) {
    const float* X = (bid >= 864) ? k2 : k1;
    ush* O = (bid >= 864) ? k2f : k1f;
    const int rows = (bid >= 864) ? 1440 : 1728;
    const int bx = (bid >= 864) ? bid - 864 : bid;
    const int tiles = (rows + 15) >> 4;
    const int g = bx * 4 + (t >> 6);
    if (g < tiles * 32) conv_body(X, O, rows, g);
  } else if (bid < 2496) {
    const int x = bid - 1728;
    const int bb = x >> 4;
    const int nt = ((x & 15) << 2) + (t >> 6);
    const int c = lane & 15, q = lane >> 4;
    float v[8];
#pragma unroll
    for (int j = 0; j < 8; ++j) {
      int l = q * 8 + j;
      v[j] = (l < LL) ? G2a[(size_t)(bb * LL + l) * D + nt * 16 + c] : 0.f;
    }
    bf16x8 hi, lo;
    split8(v, hi, lo);
    bf16x8* o = (bf16x8*)(G2aF + ((size_t)(bb * 64 + nt) * 2) * 512 + lane * 8);
    o[0] = hi;
    o[64] = lo;
  } else {
    const int x = bid - 2496;
    const int aa = x >> 4;
    const int nt = ((x & 15) << 2) + (t >> 6);
    const int c = lane & 15, q = lane >> 4;
#pragma unroll
    for (int kc = 0; kc < 2; ++kc) {
      float v[8];
#pragma unroll
      for (int j = 0; j < 8; ++j) {
        int r = kc * 32 + q * 8 + j;
        v[j] = (r < RR) ? G1b[(size_t)(aa * RR + r) * D + nt * 16 + c] : 0.f;
      }
      bf16x8 hi, lo;
      split8(v, hi, lo);
      bf16x8* o = (bf16x8*)(G1bF + (((size_t)(aa * 64 + nt) * 2 + kc) * 2) * 512 + lane * 8);
      o[0] = hi;
      o[64] = lo;
    }
  }
}

// ---- split-bf16 MFMA GEMM core: each wave 4x4 16-tiles, direct frag loads ----
__device__ __forceinline__ void gemm4_body(const bf16x8* __restrict__ Af,
                                           const bf16x8* __restrict__ Bf,
                                           float* __restrict__ C,
                                           int M, int N, float scale,
                                           int Mtiles, int Ntiles) {
  const int lane = threadIdx.x & 63;
  const int w = threadIdx.x >> 6;
  const int mb = blockIdx.y * 8 + (w >> 1) * 4;
  const int nb = blockIdx.x * 8 + (w & 1) * 4;
  size_t ab[4], bb[4];
#pragma unroll
  for (int i = 0; i < 4; ++i) {
    int tm = mb + i; if (tm > Mtiles - 1) tm = Mtiles - 1;
    ab[i] = (size_t)tm * 4096 + lane;
    int tn = nb + i; if (tn > Ntiles - 1) tn = Ntiles - 1;
    bb[i] = (size_t)tn * 4096 + lane;
  }
  f32x4 acc[4][4];
#pragma unroll
  for (int i = 0; i < 4; ++i)
#pragma unroll
    for (int j = 0; j < 4; ++j) acc[i][j] = (f32x4){0.f, 0.f, 0.f, 0.f};
#pragma unroll 1
  for (int kc = 0; kc < 32; ++kc) {
    bf16x8 ah[4], al[4], bh[4], bl[4];
#pragma unroll
    for (int i = 0; i < 4; ++i) { ah[i] = Af[ab[i]]; al[i] = Af[ab[i] + 64]; ab[i] += 128; }
#pragma unroll
    for (int j = 0; j < 4; ++j) { bh[j] = Bf[bb[j]]; bl[j] = Bf[bb[j] + 64]; bb[j] += 128; }
#pragma unroll
    for (int i = 0; i < 4; ++i)
#pragma unroll
      for (int j = 0; j < 4; ++j) {
        acc[i][j] = MFMA16(ah[i], bh[j], acc[i][j]);
        acc[i][j] = MFMA16(al[i], bh[j], acc[i][j]);
        acc[i][j] = MFMA16(ah[i], bl[j], acc[i][j]);
      }
  }
  const int c16 = lane & 15, q = lane >> 4;
#pragma unroll
  for (int i = 0; i < 4; ++i) {
#pragma unroll
    for (int reg = 0; reg < 4; ++reg) {
      int r = (mb + i) * 16 + q * 4 + reg;
      if (r < M) {
#pragma unroll
        for (int j = 0; j < 4; ++j) {
          int col = (nb + j) * 16 + c16;
          if (col < N) C[(size_t)r * N + col] = acc[i][j][reg] * scale;
        }
      }
    }
  }
}

// 4 projection GEMMs in one launch. grid (8, 14, 4)
__global__ __launch_bounds__(256) void proj_fused(
    const bf16x8* __restrict__ v1f, const bf16x8* __restrict__ v2f,
    const bf16x8* __restrict__ wimgf, const bf16x8* __restrict__ wtxtf,
    const bf16x8* __restrict__ w1af, const bf16x8* __restrict__ w1bf,
    float* k1, float* k2, float* G2a, float* G1b) {
  const int z = blockIdx.z;
  const bf16x8* Af = (z == 0 || z == 3) ? v1f : v2f;
  const bf16x8* Bf = (z == 0) ? wimgf : (z == 1) ? wtxtf : (z == 2) ? w1af : w1bf;
  float* C = (z == 0) ? k1 : (z == 1) ? k2 : (z == 2) ? G2a : G1b;
  const int M = (z == 0 || z == 3) ? 1728 : 1440;
  const int Mt = (z == 0 || z == 3) ? 108 : 92;
  if ((int)blockIdx.y * 8 >= Mt) return;
  gemm4_body(Af, Bf, C, M, 1024, 1.f, Mt, 64);
}

// 2 cross GEMMs in one launch. grid (14, 12, 2)
__global__ __launch_bounds__(256) void cross_fused(
    const bf16x8* __restrict__ k2f, const bf16x8* __restrict__ k1f,
    const bf16x8* __restrict__ v2f, const bf16x8* __restrict__ v1f,
    float* Sbuf, float* Cbuf) {
  if (blockIdx.z == 0) gemm4_body(k2f, k1f, Sbuf, 1440, 1728, 0.03125f, 92, 108);
  else                 gemm4_body(v2f, v1f, Cbuf, 1440, 1728, 1.f, 92, 108);
}

// ---- Gram partials: grid (8, 96) ----
__global__ __launch_bounds__(256) void gram_partial(const float* __restrict__ v1,
                                                    const float* __restrict__ v2,
                                                    float* __restrict__ pg) {
  const int y = blockIdx.y, cx = blockIdx.x;
  const int isV1 = y < 48;
  const int batch = isV1 ? y : y - 48;
  const int Nr = isV1 ? RR : LL;
  const float* base = isV1 ? v1 + (size_t)batch * RR * D : v2 + (size_t)batch * LL * D;
  __shared__ __align__(16) float vs[36][132];
  const int t = threadIdx.x;
  for (int idx = t; idx < Nr * 32; idx += 256) {
    int row = idx >> 5, c4 = idx & 31;
    *(float4*)&vs[row][c4 * 4] = *(const float4*)&base[(size_t)row * D + cx * 128 + c4 * 4];
  }
  __syncthreads();
  const int nt3 = Nr / 3;
  float acc[3][3] = {{0.f,0.f,0.f},{0.f,0.f,0.f},{0.f,0.f,0.f}};
  const int i0 = (t / nt3) * 3, j0 = (t - (t / nt3) * nt3) * 3;
  if (t < nt3 * nt3) {
    for (int k4 = 0; k4 < 32; ++k4) {
      float4 a[3], b[3];
#pragma unroll
      for (int ii = 0; ii < 3; ++ii) a[ii] = *(const float4*)&vs[i0 + ii][k4 * 4];
#pragma unroll
      for (int jj = 0; jj < 3; ++jj) b[jj] = *(const float4*)&vs[j0 + jj][k4 * 4];
#pragma unroll
      for (int ii = 0; ii < 3; ++ii)
#pragma unroll
        for (int jj = 0; jj < 3; ++jj) {
          acc[ii][jj] = fmaf(a[ii].x, b[jj].x, acc[ii][jj]);
          acc[ii][jj] = fmaf(a[ii].y, b[jj].y, acc[ii][jj]);
          acc[ii][jj] = fmaf(a[ii].z, b[jj].z, acc[ii][jj]);
          acc[ii][jj] = fmaf(a[ii].w, b[jj].w, acc[ii][jj]);
        }
    }
    float* o = pg + ((size_t)y * 8 + cx) * 1296;
#pragma unroll
    for (int ii = 0; ii < 3; ++ii)
#pragma unroll
      for (int jj = 0; jj < 3; ++jj) o[(i0 + ii) * Nr + (j0 + jj)] = acc[ii][jj];
  }
}

__global__ __launch_bounds__(256) void gram_reduce(const float* __restrict__ pg,
                                                   float* __restrict__ g11,
                                                   float* __restrict__ g22) {
  const int y = blockIdx.x;
  const int isV1 = y < 48;
  const int batch = isV1 ? y : y - 48;
  const int NN = isV1 ? RR * RR : LL * LL;
  const float* p = pg + (size_t)y * 8 * 1296;
  float* o = isV1 ? g11 + (size_t)batch * RR * RR : g22 + (size_t)batch * LL * LL;
  for (int i = threadIdx.x; i < NN; i += 256) {
    float s = 0.f;
#pragma unroll
    for (int c = 0; c < 8; ++c) s += p[c * 1296 + i];
    o[i] = s;
  }
}

// ---- batched MLP score kernel: grid 288 (dirA) + 384 (dirB) ----
__global__ __launch_bounds__(256) void score_kernel(
    const float* __restrict__ Sb,
    const bf16x8* __restrict__ G2aF, const bf16x8* __restrict__ G1bF,
    const float* __restrict__ b1a, const float* __restrict__ w2a,
    const float* __restrict__ b1b, const float* __restrict__ w2b,
    float* __restrict__ saBuf, float* __restrict__ sbBuf) {
  __shared__ ush frag[24576];   // 48 KB
  const int t = threadIdx.x, lane = t & 63, w = t >> 6;
  const int c16 = lane & 15, q = lane >> 4;
  const int bid = blockIdx.x;

  for (int i = t; i < 3072; i += 256) ((int4*)frag)[i] = make_int4(0, 0, 0, 0);
  __syncthreads();

  if (bid < 288) {
    // direction A: fixed b, pairs a = ag*8..+7. H[r][e]=b1a[e]+sum_l p2[r][l]G2a[b][l][e]
    const int b = bid / 6, ag = bid % 6;
    for (int cc = t; cc < 8 * RR; cc += 256) {
      const int pp = cc / RR, r = cc - pp * RR;
      const int a = ag * 8 + pp;
      const float* sp = Sb + (size_t)(b * LL) * 1728 + a * RR + r;
      float v[LL];
      float m = -1e30f;
#pragma unroll
      for (int l = 0; l < LL; ++l) { v[l] = sp[(size_t)l * 1728]; m = fmaxf(m, v[l]); }
      float s = 0.f;
#pragma unroll
      for (int l = 0; l < LL; ++l) { v[l] = __expf(v[l] - m); s += v[l]; }
      const float inv = 1.f / s;
      ush* base = frag + (pp * 3 + (r >> 4)) * 1024;
      const int mr = r & 15;
#pragma unroll
      for (int l = 0; l < LL; ++l) {
        float p = v[l] * inv;
        ush hi = f2bf(p);
        ush lo = f2bf(p - bf2f(hi));
        int idx = (((l >> 3) * 16 + mr) << 3) + (l & 7);
        base[idx] = hi; base[512 + idx] = lo;
      }
    }
    __syncthreads();
    const int nt0 = w * 16;
#pragma unroll 1
    for (int g = 0; g < 4; ++g) {
      bf16x8 Ah[6], Al[6];
#pragma unroll
      for (int i = 0; i < 6; ++i) {
        const ush* p = frag + (g * 6 + i) * 1024 + lane * 8;
        Ah[i] = *(const bf16x8*)p;
        Al[i] = *(const bf16x8*)(p + 512);
      }
      float scP[6][4][4];
#pragma unroll
      for (int i = 0; i < 6; ++i)
#pragma unroll
        for (int reg = 0; reg < 4; ++reg)
#pragma unroll
          for (int h = 0; h < NH; ++h) scP[i][reg][h] = 0.f;
#pragma unroll 2
      for (int nt = nt0; nt < nt0 + 16; ++nt) {
        const bf16x8* gp = G2aF + (size_t)(b * 64 + nt) * 128 + lane;
        bf16x8 Bh = gp[0], Bl = gp[64];
        const int col = nt * 16 + c16;
        const float bias = b1a[col];
        const float w0 = w2a[col], w1 = w2a[D + col], w2v = w2a[2 * D + col], w3 = w2a[3 * D + col];
#pragma unroll
        for (int i = 0; i < 6; ++i) {
          f32x4 acc = {bias, bias, bias, bias};
          acc = MFMA16(Ah[i], Bh, acc);
          acc = MFMA16(Al[i], Bh, acc);
          acc = MFMA16(Ah[i], Bl, acc);
#pragma unroll
          for (int reg = 0; reg < 4; ++reg) {
            float hv = fmaxf(acc[reg], 0.f);
            scP[i][reg][0] = fmaf(hv, w0, scP[i][reg][0]);
            scP[i][reg][1] = fmaf(hv, w1, scP[i][reg][1]);
            scP[i][reg][2] = fmaf(hv, w2v, scP[i][reg][2]);
            scP[i][reg][3] = fmaf(hv, w3, scP[i][reg][3]);
          }
        }
      }
#pragma unroll
      for (int i = 0; i < 6; ++i) {
        const int T = g * 6 + i, pp = T / 3, mtl = T - pp * 3;
        const int pair = (ag * 8 + pp) * 48 + b;
#pragma unroll
        for (int reg = 0; reg < 4; ++reg) {
          const int r = mtl * 16 + q * 4 + reg;
#pragma unroll
          for (int h = 0; h < NH; ++h) {
            float v = scP[i][reg][h];
            v += __shfl_xor(v, 1); v += __shfl_xor(v, 2);
            v += __shfl_xor(v, 4); v += __shfl_xor(v, 8);
            if (c16 == 0 && r < RR) atomicAdd(&saBuf[(size_t)pair * 144 + r * 4 + h], v);
          }
        }
      }
    }
  } else {
    // direction B: fixed a, pairs b = bg*6..+5. H[l][e]=b1b[e]+sum_r p1[l][r]G1b[a][r][e]
    const int bid2 = bid - 288;
    const int a = bid2 / 8, bg = bid2 % 8;
    for (int cc = t; cc < 6 * LL; cc += 256) {
      const int pp = cc / LL, l = cc - pp * LL;
      const int b = bg * 6 + pp;
      const float* sp = Sb + (size_t)(b * LL + l) * 1728 + a * RR;
      float v[RR];
      float m = -1e30f;
#pragma unroll
      for (int r = 0; r < RR; ++r) { v[r] = sp[r]; m = fmaxf(m, v[r]); }
      float s = 0.f;
#pragma unroll
      for (int r = 0; r < RR; ++r) { v[r] = __expf(v[r] - m); s += v[r]; }
      const float inv = 1.f / s;
      ush* base = frag + ((pp * 2 + (l >> 4)) * 2) * 1024;
      const int mr = l & 15;
#pragma unroll
      for (int r = 0; r < RR; ++r) {
        float p = v[r] * inv;
        ush hi = f2bf(p);
        ush lo = f2bf(p - bf2f(hi));
        const int kc = r >> 5, k = r & 31;
        int idx = kc * 1024 + (((k >> 3) * 16 + mr) << 3) + (k & 7);
        base[idx] = hi; base[512 + idx] = lo;
      }
    }
    __syncthreads();
    const int nt0 = w * 16;
#pragma unroll 1
    for (int g = 0; g < 4; ++g) {
      bf16x8 A0h[3], A0l[3], A1h[3], A1l[3];
#pragma unroll
      for (int i = 0; i < 3; ++i) {
        const ush* p = frag + (g * 3 + i) * 2048 + lane * 8;
        A0h[i] = *(const bf16x8*)p;
        A0l[i] = *(const bf16x8*)(p + 512);
        A1h[i] = *(const bf16x8*)(p + 1024);
        A1l[i] = *(const bf16x8*)(p + 1536);
      }
      float scP[3][4][4];
#pragma unroll
      for (int i = 0; i < 3; ++i)
#pragma unroll
        for (int reg = 0; reg < 4; ++reg)
#pragma unroll
          for (int h = 0; h < NH; ++h) scP[i][reg][h] = 0.f;
#pragma unroll 2
      for (int nt = nt0; nt < nt0 + 16; ++nt) {
        const bf16x8* gp = G1bF + (size_t)(a * 64 + nt) * 256 + lane;
        bf16x8 B0h = gp[0], B0l = gp[64], B1h = gp[128], B1l = gp[192];
        const int col = nt * 16 + c16;
        const float bias = b1b[col];
        const float w0 = w2b[col], w1 = w2b[D + col], w2v = w2b[2 * D + col], w3 = w2b[3 * D + col];
#pragma unroll
        for (int i = 0; i < 3; ++i) {
          f32x4 acc = {bias, bias, bias, bias};
          acc = MFMA16(A0h[i], B0h, acc);
          acc = MFMA16(A0l[i], B0h, acc);
          acc = MFMA16(A0h[i], B0l, acc);
          acc = MFMA16(A1h[i], B1h, acc);
          acc = MFMA16(A1l[i], B1h, acc);
          acc = MFMA16(A1h[i], B1l, acc);
#pragma unroll
          for (int reg = 0; reg < 4; ++reg) {
            float hv = fmaxf(acc[reg], 0.f);
            scP[i][reg][0] = fmaf(hv, w0, scP[i][reg][0]);
            scP[i][reg][1] = fmaf(hv, w1, scP[i][reg][1]);
            scP[i][reg][2] = fmaf(hv, w2v, scP[i][reg][2]);
            scP[i][reg][3] = fmaf(hv, w3, scP[i][reg][3]);
          }
        }
      }
#pragma unroll
      for (int i = 0; i < 3; ++i) {
        const int T = g * 3 + i, pp = T >> 1, mtl = T & 1;
        const int pair = a * 48 + bg * 6 + pp;
#pragma unroll
        for (int reg = 0; reg < 4; ++reg) {
          const int l = mtl * 16 + q * 4 + reg;
#pragma unroll
          for (int h = 0; h < NH; ++h) {
            float v = scP[i][reg][h];
            v += __shfl_xor(v, 1); v += __shfl_xor(v, 2);
            v += __shfl_xor(v, 4); v += __shfl_xor(v, 8);
            if (c16 == 0 && l < LL) atomicAdd(&sbBuf[(size_t)pair * 120 + l * 4 + h], v);
          }
        }
      }
    }
  }
}

// ---- finalize: head softmax, u-vectors, bilinears. grid 2304 ----
__global__ __launch_bounds__(256) void finalize_kernel(
    const float* __restrict__ Sb, const float* __restrict__ Cb,
    const float* __restrict__ g22, const float* __restrict__ g11,
    const float* __restrict__ saBuf, const float* __restrict__ sbBuf,
    float* __restrict__ out) {
  const int pair = blockIdx.x;
  const int a = pair / NB2;
  const int b = pair - a * NB2;
  const int t = threadIdx.x, w = t >> 6;

  __shared__ float sS[LL][RR];
  __shared__ float p1s[LL][RR];
  __shared__ float p2s[RR][32];
  __shared__ float sa[RR][NH];
  __shared__ float sbm[LL][NH];
  __shared__ float qa[RR], qb[LL], u1[RR], u2[LL];
  __shared__ float redbuf[3][4];

  for (int i = t; i < LL * RR; i += 256) {
    int l = i / RR, r = i - l * RR;
    sS[l][r] = Sb[(size_t)(b * LL + l) * 1728 + a * RR + r];
  }
  if (t < RR * NH) ((float*)sa)[t] = saBuf[(size_t)pair * 144 + t];
  if (t >= 128 && t < 128 + LL * NH) ((float*)sbm)[t - 128] = sbBuf[(size_t)pair * 120 + (t - 128)];
  __syncthreads();

  // p1 row softmax over r; p2 column softmax over l
  if (t < LL) {
    float m = -1e30f;
    for (int r = 0; r < RR; ++r) m = fmaxf(m, sS[t][r]);
    float s = 0.f;
    for (int r = 0; r < RR; ++r) { float e = __expf(sS[t][r] - m); p1s[t][r] = e; s += e; }
    float inv = 1.f / s;
    for (int r = 0; r < RR; ++r) p1s[t][r] *= inv;
  } else if (t >= 64 && t < 64 + RR) {
    int r = t - 64;
    float m = -1e30f;
    for (int l = 0; l < LL; ++l) m = fmaxf(m, sS[l][r]);
    float s = 0.f;
    for (int l = 0; l < LL; ++l) { float e = __expf(sS[l][r] - m); p2s[r][l] = e; s += e; }
    float inv = 1.f / s;
    for (int l = 0; l < LL; ++l) p2s[r][l] *= inv;
  } else if (t >= 128 && t < 128 + NH) {
    const int h = t - 128;
    float m = -1e30f;
    for (int r = 0; r < RR; ++r) m = fmaxf(m, sa[r][h]);
    float s = 0.f;
    for (int r = 0; r < RR; ++r) { float e = __expf(sa[r][h] - m); sa[r][h] = e; s += e; }
    float inv = 1.f / s;
    for (int r = 0; r < RR; ++r) sa[r][h] *= inv;
  } else if (t >= 192 && t < 192 + NH) {
    const int h = t - 192;
    float m = -1e30f;
    for (int l = 0; l < LL; ++l) m = fmaxf(m, sbm[l][h]);
    float s = 0.f;
    for (int l = 0; l < LL; ++l) { float e = __expf(sbm[l][h] - m); sbm[l][h] = e; s += e; }
    float inv = 1.f / s;
    for (int l = 0; l < LL; ++l) sbm[l][h] *= inv;
  }
  __syncthreads();
  if (t < RR) qa[t] = 0.25f * (sa[t][0] + sa[t][1] + sa[t][2] + sa[t][3]);
  else if (t >= 64 && t < 64 + LL) {
    int l = t - 64;
    qb[l] = 0.25f * (sbm[l][0] + sbm[l][1] + sbm[l][2] + sbm[l][3]);
  }
  __syncthreads();

  if (t < LL) {
    float x = 0.f;
    for (int r = 0; r < RR; ++r) x = fmaf(qa[r], p2s[r][t], x);
    u2[t] = x;
  } else if (t >= 64 && t < 64 + RR) {
    int r = t - 64;
    float x = 0.f;
    for (int l = 0; l < LL; ++l) x = fmaf(qb[l], p1s[l][r], x);
    u1[r] = x;
  }
  __syncthreads();

  float pnum = 0.f, pn1 = 0.f, pn2 = 0.f;
  {
    const float* Cab = Cb + (size_t)(b * LL) * 1728 + a * RR;
    for (int i = t; i < LL * RR; i += 256) {
      int l = i / RR, r = i - l * RR;
      pnum = fmaf(u2[l] * u1[r], Cab[(size_t)l * 1728 + r], pnum);
    }
    const float* G22 = g22 + (size_t)b * LL * LL;
    for (int i = t; i < LL * LL; i += 256) {
      int l = i / LL, l2 = i - l * LL;
      pn1 = fmaf(u2[l] * u2[l2], G22[i], pn1);
    }
    const float* G11 = g11 + (size_t)a * RR * RR;
    for (int i = t; i < RR * RR; i += 256) {
      int r = i / RR, r2 = i - r * RR;
      pn2 = fmaf(u1[r] * u1[r2], G11[i], pn2);
    }
  }
#pragma unroll
  for (int off = 32; off > 0; off >>= 1) {
    pnum += __shfl_down(pnum, off);
    pn1  += __shfl_down(pn1, off);
    pn2  += __shfl_down(pn2, off);
  }
  if ((t & 63) == 0) { redbuf[0][w] = pnum; redbuf[1][w] = pn1; redbuf[2][w] = pn2; }
  __syncthreads();
  if (t == 0) {
    float num = redbuf[0][0] + redbuf[0][1] + redbuf[0][2] + redbuf[0][3];
    float n1s = redbuf[1][0] + redbuf[1][1] + redbuf[1][2] + redbuf[1][3];
    float n2s = redbuf[2][0] + redbuf[2][1] + redbuf[2][2] + redbuf[2][3];
    float n1 = sqrtf(fmaxf(n1s, 0.f));
    float n2 = sqrtf(fmaxf(n2s, 0.f));
    out[pair] = num / ((n1 + 1e-8f) * (n2 + 1e-8f));
  }
}

extern "C" void kernel_launch(void* const* d_in, const int* in_sizes, int n_in,
                              void* d_out, int out_size, void* d_ws, size_t ws_size,
                              hipStream_t stream) {
  const float* v1    = (const float*)d_in[0];
  const float* v2    = (const float*)d_in[1];
  const float* w_img = (const float*)d_in[2];
  const float* w_txt = (const float*)d_in[3];
  const float* w1a   = (const float*)d_in[4];
  const float* b1a   = (const float*)d_in[5];
  const float* w2a   = (const float*)d_in[6];
  const float* w1b   = (const float*)d_in[8];
  const float* b1b   = (const float*)d_in[9];
  const float* w2b   = (const float*)d_in[10];
  float* out = (float*)d_out;

  float* ws   = (float*)d_ws;
  float* k1   = ws;
  float* k2   = k1 + (size_t)1728 * 1024;
  float* G2a  = k2 + (size_t)1440 * 1024;
  float* G1b  = G2a + (size_t)1440 * 1024;
  float* Sbuf = G1b + (size_t)1728 * 1024;
  float* Cbuf = Sbuf + (size_t)1440 * 1728;
  float* g22  = Cbuf + (size_t)1440 * 1728;
  float* g11  = g22 + (size_t)48 * 900;

  ush* fb    = (ush*)(g11 + (size_t)48 * 1296);
  ush* v1f   = fb;
  ush* v2f   = v1f + (size_t)108 * 32768;
  ush* k1f   = v2f + (size_t)92 * 32768;
  ush* k2f   = k1f + (size_t)108 * 32768;
  ush* wimgf = k2f + (size_t)92 * 32768;
  ush* wtxtf = wimgf + (size_t)64 * 32768;
  ush* w1af  = wtxtf + (size_t)64 * 32768;
  ush* w1bf  = w1af + (size_t)64 * 32768;
  ush* G2aF  = w1bf + (size_t)64 * 32768;
  ush* G1bF  = G2aF + (size_t)48 * 65536;
  float* saBuf = (float*)(G1bF + (size_t)48 * 131072);   // 2304*144
  float* sbBuf = saBuf + (size_t)2304 * 144;             // 2304*120

  float* pg = (float*)k1f;   // gram partials alias k1f (written later)

  hipMemsetAsync(saBuf, 0, (size_t)2304 * (144 + 120) * sizeof(float), stream);

  conv6<<<dim3(864, 6), 256, 0, stream>>>(v1, v2, w_img, w_txt, w1a, w1b,
                                          v1f, v2f, wimgf, wtxtf, w1af, w1bf);
  gram_partial<<<dim3(8, 96), 256, 0, stream>>>(v1, v2, pg);
  gram_reduce<<<96, 256, 0, stream>>>(pg, g11, g22);

  proj_fused<<<dim3(8, 14, 4), 256, 0, stream>>>(
      (const bf16x8*)v1f, (const bf16x8*)v2f, (const bf16x8*)wimgf,
      (const bf16x8*)wtxtf, (const bf16x8*)w1af, (const bf16x8*)w1bf,
      k1, k2, G2a, G1b);

  conv_post<<<3264, 256, 0, stream>>>(k1, k2, G2a, G1b, k1f, k2f, G2aF, G1bF);

  cross_fused<<<dim3(14, 12, 2), 256, 0, stream>>>(
      (const bf16x8*)k2f, (const bf16x8*)k1f, (const bf16x8*)v2f, (const bf16x8*)v1f,
      Sbuf, Cbuf);

  score_kernel<<<672, 256, 0, stream>>>(Sbuf, (const bf16x8*)G2aF, (const bf16x8*)G1bF,
                                        b1a, w2a, b1b, w2b, saBuf, sbBuf);

  finalize_kernel<<<2304, 256, 0, stream>>>(Sbuf, Cbuf, g22, g11, saBuf, sbBuf, out);
}

// Round 6
// 427.006 us; speedup vs baseline: 1.1701x; 1.1701x over previous
//
#include <hip/hip_runtime.h>

#define D 1024
#define NB1 48
#define NB2 48
#define RR 36
#define LL 30
#define NH 4

typedef short bf16x8 __attribute__((ext_vector_type(8)));
typedef float f32x4 __attribute__((ext_vector_type(4)));
typedef unsigned short u16x8 __attribute__((ext_vector_type(8)));
typedef unsigned short ush;

#define MFMA16(a, b, c) __builtin_amdgcn_mfma_f32_16x16x32_bf16(a, b, c, 0, 0, 0)

__device__ __forceinline__ ush f2bf(float x) {
  unsigned u = __float_as_uint(x);
  u += 0x7FFF + ((u >> 16) & 1);
  return (ush)(u >> 16);
}
__device__ __forceinline__ float bf2f(ush h) {
  return __uint_as_float(((unsigned)h) << 16);
}
__device__ __forceinline__ void split8(const float* v, bf16x8& h8, bf16x8& l8) {
  u16x8 hi, lo;
#pragma unroll
  for (int i = 0; i < 8; ++i) {
    ush h = f2bf(v[i]);
    hi[i] = h;
    lo[i] = f2bf(v[i] - bf2f(h));
  }
  h8 = __builtin_bit_cast(bf16x8, hi);
  l8 = __builtin_bit_cast(bf16x8, lo);
}

// ---- fp32 row-major (rows x 1024) -> split-bf16 MFMA fragment layout ----
__device__ __forceinline__ void conv_body(const float* __restrict__ X,
                                          ush* __restrict__ out,
                                          int rows, int g) {
  const int lane = threadIdx.x & 63;
  const int tile = g >> 5, kc = g & 31;
  const int row = tile * 16 + (lane & 15);
  const int k = kc * 32 + (lane >> 4) * 8;
  float v[8];
  if (row < rows) {
    const float4* s = (const float4*)(X + (size_t)row * 1024 + k);
    float4 x0 = s[0], x1 = s[1];
    v[0] = x0.x; v[1] = x0.y; v[2] = x0.z; v[3] = x0.w;
    v[4] = x1.x; v[5] = x1.y; v[6] = x1.z; v[7] = x1.w;
  } else {
#pragma unroll
    for (int i = 0; i < 8; ++i) v[i] = 0.f;
  }
  bf16x8 hi, lo;
  split8(v, hi, lo);
  bf16x8* o = (bf16x8*)(out + (size_t)g * 1024 + lane * 8);
  o[0] = hi;
  o[64] = lo;
}

// 6 input matrices in one launch. grid (864, 6)
__global__ __launch_bounds__(256) void conv6(
    const float* __restrict__ v1, const float* __restrict__ v2,
    const float* __restrict__ wimg, const float* __restrict__ wtxt,
    const float* __restrict__ w1a, const float* __restrict__ w1b,
    ush* v1f, ush* v2f, ush* wimgf, ush* wtxtf, ush* w1af, ush* w1bf) {
  const float* X; ush* O; int rows;
  switch (blockIdx.y) {
    case 0: X = v1; O = v1f; rows = 1728; break;
    case 1: X = v2; O = v2f; rows = 1440; break;
    case 2: X = wimg; O = wimgf; rows = 1024; break;
    case 3: X = wtxt; O = wtxtf; rows = 1024; break;
    case 4: X = w1a; O = w1af; rows = 1024; break;
    default: X = w1b; O = w1bf; rows = 1024; break;
  }
  const int tiles = (rows + 15) >> 4;
  const int g = blockIdx.x * 4 + (threadIdx.x >> 6);
  if (g >= tiles * 32) return;
  conv_body(X, O, rows, g);
}

// merged: conv k1,k2 + convG. 1D grid 3264 blocks.
__global__ __launch_bounds__(256) void conv_post(
    const float* __restrict__ k1, const float* __restrict__ k2,
    const float* __restrict__ G2a, const float* __restrict__ G1b,
    ush* k1f, ush* k2f, ush* G2aF, ush* G1bF) {
  const int bid = blockIdx.x;
  const int t = threadIdx.x, lane = t & 63;
  if (bid < 1728) {
    const float* X = (bid >= 864) ? k2 : k1;
    ush* O = (bid >= 864) ? k2f : k1f;
    const int rows = (bid >= 864) ? 1440 : 1728;
    const int bx = (bid >= 864) ? bid - 864 : bid;
    const int tiles = (rows + 15) >> 4;
    const int g = bx * 4 + (t >> 6);
    if (g < tiles * 32) conv_body(X, O, rows, g);
  } else if (bid < 2496) {
    const int x = bid - 1728;
    const int bb = x >> 4;
    const int nt = ((x & 15) << 2) + (t >> 6);
    const int c = lane & 15, q = lane >> 4;
    float v[8];
#pragma unroll
    for (int j = 0; j < 8; ++j) {
      int l = q * 8 + j;
      v[j] = (l < LL) ? G2a[(size_t)(bb * LL + l) * D + nt * 16 + c] : 0.f;
    }
    bf16x8 hi, lo;
    split8(v, hi, lo);
    bf16x8* o = (bf16x8*)(G2aF + ((size_t)(bb * 64 + nt) * 2) * 512 + lane * 8);
    o[0] = hi;
    o[64] = lo;
  } else {
    const int x = bid - 2496;
    const int aa = x >> 4;
    const int nt = ((x & 15) << 2) + (t >> 6);
    const int c = lane & 15, q = lane >> 4;
#pragma unroll
    for (int kc = 0; kc < 2; ++kc) {
      float v[8];
#pragma unroll
      for (int j = 0; j < 8; ++j) {
        int r = kc * 32 + q * 8 + j;
        v[j] = (r < RR) ? G1b[(size_t)(aa * RR + r) * D + nt * 16 + c] : 0.f;
      }
      bf16x8 hi, lo;
      split8(v, hi, lo);
      bf16x8* o = (bf16x8*)(G1bF + (((size_t)(aa * 64 + nt) * 2 + kc) * 2) * 512 + lane * 8);
      o[0] = hi;
      o[64] = lo;
    }
  }
}

// ---- split-bf16 MFMA GEMM core: each wave 4x4 16-tiles, direct frag loads ----
__device__ __forceinline__ void gemm4_body(const bf16x8* __restrict__ Af,
                                           const bf16x8* __restrict__ Bf,
                                           float* __restrict__ C,
                                           int M, int N, float scale,
                                           int Mtiles, int Ntiles) {
  const int lane = threadIdx.x & 63;
  const int w = threadIdx.x >> 6;
  const int mb = blockIdx.y * 8 + (w >> 1) * 4;
  const int nb = blockIdx.x * 8 + (w & 1) * 4;
  size_t ab[4], bb[4];
#pragma unroll
  for (int i = 0; i < 4; ++i) {
    int tm = mb + i; if (tm > Mtiles - 1) tm = Mtiles - 1;
    ab[i] = (size_t)tm * 4096 + lane;
    int tn = nb + i; if (tn > Ntiles - 1) tn = Ntiles - 1;
    bb[i] = (size_t)tn * 4096 + lane;
  }
  f32x4 acc[4][4];
#pragma unroll
  for (int i = 0; i < 4; ++i)
#pragma unroll
    for (int j = 0; j < 4; ++j) acc[i][j] = (f32x4){0.f, 0.f, 0.f, 0.f};
#pragma unroll 1
  for (int kc = 0; kc < 32; ++kc) {
    bf16x8 ah[4], al[4], bh[4], bl[4];
#pragma unroll
    for (int i = 0; i < 4; ++i) { ah[i] = Af[ab[i]]; al[i] = Af[ab[i] + 64]; ab[i] += 128; }
#pragma unroll
    for (int j = 0; j < 4; ++j) { bh[j] = Bf[bb[j]]; bl[j] = Bf[bb[j] + 64]; bb[j] += 128; }
#pragma unroll
    for (int i = 0; i < 4; ++i)
#pragma unroll
      for (int j = 0; j < 4; ++j) {
        acc[i][j] = MFMA16(ah[i], bh[j], acc[i][j]);
        acc[i][j] = MFMA16(al[i], bh[j], acc[i][j]);
        acc[i][j] = MFMA16(ah[i], bl[j], acc[i][j]);
      }
  }
  const int c16 = lane & 15, q = lane >> 4;
#pragma unroll
  for (int i = 0; i < 4; ++i) {
#pragma unroll
    for (int reg = 0; reg < 4; ++reg) {
      int r = (mb + i) * 16 + q * 4 + reg;
      if (r < M) {
#pragma unroll
        for (int j = 0; j < 4; ++j) {
          int col = (nb + j) * 16 + c16;
          if (col < N) C[(size_t)r * N + col] = acc[i][j][reg] * scale;
        }
      }
    }
  }
}

// 4 projection GEMMs in one launch. grid (8, 14, 4)
__global__ __launch_bounds__(256) void proj_fused(
    const bf16x8* __restrict__ v1f, const bf16x8* __restrict__ v2f,
    const bf16x8* __restrict__ wimgf, const bf16x8* __restrict__ wtxtf,
    const bf16x8* __restrict__ w1af, const bf16x8* __restrict__ w1bf,
    float* k1, float* k2, float* G2a, float* G1b) {
  const int z = blockIdx.z;
  const bf16x8* Af = (z == 0 || z == 3) ? v1f : v2f;
  const bf16x8* Bf = (z == 0) ? wimgf : (z == 1) ? wtxtf : (z == 2) ? w1af : w1bf;
  float* C = (z == 0) ? k1 : (z == 1) ? k2 : (z == 2) ? G2a : G1b;
  const int M = (z == 0 || z == 3) ? 1728 : 1440;
  const int Mt = (z == 0 || z == 3) ? 108 : 92;
  if ((int)blockIdx.y * 8 >= Mt) return;
  gemm4_body(Af, Bf, C, M, 1024, 1.f, Mt, 64);
}

// 2 cross GEMMs in one launch. grid (14, 12, 2)
__global__ __launch_bounds__(256) void cross_fused(
    const bf16x8* __restrict__ k2f, const bf16x8* __restrict__ k1f,
    const bf16x8* __restrict__ v2f, const bf16x8* __restrict__ v1f,
    float* Sbuf, float* Cbuf) {
  if (blockIdx.z == 0) gemm4_body(k2f, k1f, Sbuf, 1440, 1728, 0.03125f, 92, 108);
  else                 gemm4_body(v2f, v1f, Cbuf, 1440, 1728, 1.f, 92, 108);
}

// ---- Gram partials: grid (8, 96) ----
__global__ __launch_bounds__(256) void gram_partial(const float* __restrict__ v1,
                                                    const float* __restrict__ v2,
                                                    float* __restrict__ pg) {
  const int y = blockIdx.y, cx = blockIdx.x;
  const int isV1 = y < 48;
  const int batch = isV1 ? y : y - 48;
  const int Nr = isV1 ? RR : LL;
  const float* base = isV1 ? v1 + (size_t)batch * RR * D : v2 + (size_t)batch * LL * D;
  __shared__ __align__(16) float vs[36][132];
  const int t = threadIdx.x;
  for (int idx = t; idx < Nr * 32; idx += 256) {
    int row = idx >> 5, c4 = idx & 31;
    *(float4*)&vs[row][c4 * 4] = *(const float4*)&base[(size_t)row * D + cx * 128 + c4 * 4];
  }
  __syncthreads();
  const int nt3 = Nr / 3;
  float acc[3][3] = {{0.f,0.f,0.f},{0.f,0.f,0.f},{0.f,0.f,0.f}};
  const int i0 = (t / nt3) * 3, j0 = (t - (t / nt3) * nt3) * 3;
  if (t < nt3 * nt3) {
    for (int k4 = 0; k4 < 32; ++k4) {
      float4 a[3], b[3];
#pragma unroll
      for (int ii = 0; ii < 3; ++ii) a[ii] = *(const float4*)&vs[i0 + ii][k4 * 4];
#pragma unroll
      for (int jj = 0; jj < 3; ++jj) b[jj] = *(const float4*)&vs[j0 + jj][k4 * 4];
#pragma unroll
      for (int ii = 0; ii < 3; ++ii)
#pragma unroll
        for (int jj = 0; jj < 3; ++jj) {
          acc[ii][jj] = fmaf(a[ii].x, b[jj].x, acc[ii][jj]);
          acc[ii][jj] = fmaf(a[ii].y, b[jj].y, acc[ii][jj]);
          acc[ii][jj] = fmaf(a[ii].z, b[jj].z, acc[ii][jj]);
          acc[ii][jj] = fmaf(a[ii].w, b[jj].w, acc[ii][jj]);
        }
    }
    float* o = pg + ((size_t)y * 8 + cx) * 1296;
#pragma unroll
    for (int ii = 0; ii < 3; ++ii)
#pragma unroll
      for (int jj = 0; jj < 3; ++jj) o[(i0 + ii) * Nr + (j0 + jj)] = acc[ii][jj];
  }
}

__global__ __launch_bounds__(256) void gram_reduce(const float* __restrict__ pg,
                                                   float* __restrict__ g11,
                                                   float* __restrict__ g22) {
  const int y = blockIdx.x;
  const int isV1 = y < 48;
  const int batch = isV1 ? y : y - 48;
  const int NN = isV1 ? RR * RR : LL * LL;
  const float* p = pg + (size_t)y * 8 * 1296;
  float* o = isV1 ? g11 + (size_t)batch * RR * RR : g22 + (size_t)batch * LL * LL;
  for (int i = threadIdx.x; i < NN; i += 256) {
    float s = 0.f;
#pragma unroll
    for (int c = 0; c < 8; ++c) s += p[c * 1296 + i];
    o[i] = s;
  }
}

// ---- softmax + A-fragment precompute: grid 2304 (one per pair) ----
// p2F[pair]: 3 mt x (hi,lo) x 512 ush  (A = p2[r][l], K=32)
// p1F[pair]: 2 mt x 2 kc x (hi,lo) x 512 ush (A = p1[l][r], K=64)
__global__ __launch_bounds__(256) void softmax_frag(const float* __restrict__ Sb,
                                                    ush* __restrict__ p2F,
                                                    ush* __restrict__ p1F) {
  const int pair = blockIdx.x;
  const int a = pair / NB2;
  const int b = pair - a * NB2;
  const int t = threadIdx.x, lane = t & 63;
  __shared__ __align__(16) float sS[LL][RR];
  __shared__ __align__(16) float p2s[48][36];
  __shared__ __align__(16) float p1s[32][68];
  for (int i = t; i < 48 * 36; i += 256) ((float*)p2s)[i] = 0.f;
  for (int i = t; i < 32 * 68; i += 256) ((float*)p1s)[i] = 0.f;
  for (int i = t; i < LL * RR; i += 256) {
    int l = i / RR, r = i - l * RR;
    sS[l][r] = Sb[(size_t)(b * LL + l) * 1728 + a * RR + r];
  }
  __syncthreads();
  if (t < LL) {
    float m = -1e30f;
    for (int r = 0; r < RR; ++r) m = fmaxf(m, sS[t][r]);
    float s = 0.f;
    for (int r = 0; r < RR; ++r) { float e = __expf(sS[t][r] - m); p1s[t][r] = e; s += e; }
    float inv = 1.f / s;
    for (int r = 0; r < RR; ++r) p1s[t][r] *= inv;
  } else if (t >= 64 && t < 64 + RR) {
    int r = t - 64;
    float m = -1e30f;
    for (int l = 0; l < LL; ++l) m = fmaxf(m, sS[l][r]);
    float s = 0.f;
    for (int l = 0; l < LL; ++l) { float e = __expf(sS[l][r] - m); p2s[r][l] = e; s += e; }
    float inv = 1.f / s;
    for (int l = 0; l < LL; ++l) p2s[r][l] *= inv;
  }
  __syncthreads();
  const int mr = lane & 15, q = lane >> 4;
  if (t < 192) {
    const int mt = t >> 6;
    float v[8];
#pragma unroll
    for (int j = 0; j < 8; ++j) v[j] = p2s[mt * 16 + mr][q * 8 + j];
    bf16x8 hi, lo;
    split8(v, hi, lo);
    bf16x8* o = (bf16x8*)p2F + (size_t)(pair * 3 + mt) * 128 + lane;
    o[0] = hi;
    o[64] = lo;
  }
  {
    const int mt = t >> 7, kc = (t >> 6) & 1;
    float v[8];
#pragma unroll
    for (int j = 0; j < 8; ++j) v[j] = p1s[mt * 16 + mr][kc * 32 + q * 8 + j];
    bf16x8 hi, lo;
    split8(v, hi, lo);
    bf16x8* o = (bf16x8*)p1F + (size_t)(pair * 2 + mt) * 256 + kc * 128 + lane;
    o[0] = hi;
    o[64] = lo;
  }
}

// ---- score v2: grid 2304 = 1152 dirA + 1152 dirB, LDS-staged G, eg-split x4 ----
__global__ __launch_bounds__(256) void score_kernel(
    const bf16x8* __restrict__ G2aF, const bf16x8* __restrict__ G1bF,
    const bf16x8* __restrict__ p2F, const bf16x8* __restrict__ p1F,
    const float* __restrict__ b1a, const float* __restrict__ w2a,
    const float* __restrict__ b1b, const float* __restrict__ w2b,
    float* __restrict__ saBuf, float* __restrict__ sbBuf) {
  __shared__ __align__(16) ush lds[32768];   // 64 KB
  const int t = threadIdx.x, lane = t & 63, w = t >> 6;
  const int c16 = lane & 15, q = lane >> 4;
  const int bid = blockIdx.x;

  if (bid < 1152) {
    // dirA: bid = ag*192 + (b*4+eg). ag-siblings stride 192 (same XCD for L2 reuse).
    const int ag = bid / 192;
    const int rem = bid - ag * 192;
    const int b = rem >> 2, eg = rem & 3;
    // stage 16-nt G2a slice (32 KB, contiguous)
    {
      const bf16x8* gsrc = G2aF + (size_t)(b * 64 + eg * 16) * 128;
      bf16x8* gdst = (bf16x8*)lds;
      for (int i = t; i < 2048; i += 256) gdst[i] = gsrc[i];
    }
    float* wbs = (float*)(lds + 16384);  // [5][256]
    {
      const int col = eg * 256 + t;
      wbs[t] = b1a[col];
      wbs[256 + t] = w2a[col];
      wbs[512 + t] = w2a[1024 + col];
      wbs[768 + t] = w2a[2048 + col];
      wbs[1024 + t] = w2a[3072 + col];
    }
    __syncthreads();
#pragma unroll 1
    for (int ai = 0; ai < 2; ++ai) {
      const int a = ag * 8 + w * 2 + ai;
      const int pair = a * 48 + b;
      bf16x8 Ah[3], Al[3];
#pragma unroll
      for (int mt = 0; mt < 3; ++mt) {
        const bf16x8* pp = p2F + (size_t)(pair * 3 + mt) * 128 + lane;
        Ah[mt] = pp[0];
        Al[mt] = pp[64];
      }
      float scP[3][4][NH];
#pragma unroll
      for (int mt = 0; mt < 3; ++mt)
#pragma unroll
        for (int reg = 0; reg < 4; ++reg)
#pragma unroll
          for (int h = 0; h < NH; ++h) scP[mt][reg][h] = 0.f;
#pragma unroll 2
      for (int nt = 0; nt < 16; ++nt) {
        const bf16x8* gp = (const bf16x8*)lds + nt * 128 + lane;
        bf16x8 Bh = gp[0], Bl = gp[64];
        const int cc = nt * 16 + c16;
        const float bias = wbs[cc];
        const float w0 = wbs[256 + cc], w1 = wbs[512 + cc];
        const float w2v = wbs[768 + cc], w3 = wbs[1024 + cc];
#pragma unroll
        for (int mt = 0; mt < 3; ++mt) {
          f32x4 acc = {bias, bias, bias, bias};
          acc = MFMA16(Ah[mt], Bh, acc);
          acc = MFMA16(Al[mt], Bh, acc);
          acc = MFMA16(Ah[mt], Bl, acc);
#pragma unroll
          for (int reg = 0; reg < 4; ++reg) {
            float hv = fmaxf(acc[reg], 0.f);
            scP[mt][reg][0] = fmaf(hv, w0, scP[mt][reg][0]);
            scP[mt][reg][1] = fmaf(hv, w1, scP[mt][reg][1]);
            scP[mt][reg][2] = fmaf(hv, w2v, scP[mt][reg][2]);
            scP[mt][reg][3] = fmaf(hv, w3, scP[mt][reg][3]);
          }
        }
      }
#pragma unroll
      for (int mt = 0; mt < 3; ++mt)
#pragma unroll
        for (int reg = 0; reg < 4; ++reg) {
          const int r = mt * 16 + q * 4 + reg;
#pragma unroll
          for (int h = 0; h < NH; ++h) {
            float v = scP[mt][reg][h];
            v += __shfl_xor(v, 1); v += __shfl_xor(v, 2);
            v += __shfl_xor(v, 4); v += __shfl_xor(v, 8);
            if (c16 == 0 && r < RR) atomicAdd(&saBuf[(size_t)pair * 144 + r * 4 + h], v);
          }
        }
    }
  } else {
    // dirB: bid2 = bg*192 + (a*4+eg)
    const int bid2 = bid - 1152;
    const int bg = bid2 / 192;
    const int rem = bid2 - bg * 192;
    const int a = rem >> 2, eg = rem & 3;
    {
      const bf16x8* gsrc = G1bF + (size_t)(a * 64 + eg * 16) * 256;
      bf16x8* gdst = (bf16x8*)lds;
      for (int i = t; i < 4096; i += 256) gdst[i] = gsrc[i];   // 64 KB
    }
    __syncthreads();
#pragma unroll 1
    for (int bi = 0; bi < 2; ++bi) {
      const int b = bg * 8 + w * 2 + bi;
      const int pair = a * 48 + b;
      bf16x8 Ah[2][2], Al[2][2];
#pragma unroll
      for (int mt = 0; mt < 2; ++mt)
#pragma unroll
        for (int kc = 0; kc < 2; ++kc) {
          const bf16x8* pp = p1F + (size_t)(pair * 2 + mt) * 256 + kc * 128 + lane;
          Ah[mt][kc] = pp[0];
          Al[mt][kc] = pp[64];
        }
      float scP[2][4][NH];
#pragma unroll
      for (int mt = 0; mt < 2; ++mt)
#pragma unroll
        for (int reg = 0; reg < 4; ++reg)
#pragma unroll
          for (int h = 0; h < NH; ++h) scP[mt][reg][h] = 0.f;
#pragma unroll 2
      for (int nt = 0; nt < 16; ++nt) {
        const bf16x8* gp = (const bf16x8*)lds + nt * 256 + lane;
        bf16x8 B0h = gp[0], B0l = gp[64], B1h = gp[128], B1l = gp[192];
        const int col = eg * 256 + nt * 16 + c16;
        const float bias = b1b[col];
        const float w0 = w2b[col], w1 = w2b[1024 + col];
        const float w2v = w2b[2048 + col], w3 = w2b[3072 + col];
#pragma unroll
        for (int mt = 0; mt < 2; ++mt) {
          f32x4 acc = {bias, bias, bias, bias};
          acc = MFMA16(Ah[mt][0], B0h, acc);
          acc = MFMA16(Al[mt][0], B0h, acc);
          acc = MFMA16(Ah[mt][0], B0l, acc);
          acc = MFMA16(Ah[mt][1], B1h, acc);
          acc = MFMA16(Al[mt][1], B1h, acc);
          acc = MFMA16(Ah[mt][1], B1l, acc);
#pragma unroll
          for (int reg = 0; reg < 4; ++reg) {
            float hv = fmaxf(acc[reg], 0.f);
            scP[mt][reg][0] = fmaf(hv, w0, scP[mt][reg][0]);
            scP[mt][reg][1] = fmaf(hv, w1, scP[mt][reg][1]);
            scP[mt][reg][2] = fmaf(hv, w2v, scP[mt][reg][2]);
            scP[mt][reg][3] = fmaf(hv, w3, scP[mt][reg][3]);
          }
        }
      }
#pragma unroll
      for (int mt = 0; mt < 2; ++mt)
#pragma unroll
        for (int reg = 0; reg < 4; ++reg) {
          const int l = mt * 16 + q * 4 + reg;
#pragma unroll
          for (int h = 0; h < NH; ++h) {
            float v = scP[mt][reg][h];
            v += __shfl_xor(v, 1); v += __shfl_xor(v, 2);
            v += __shfl_xor(v, 4); v += __shfl_xor(v, 8);
            if (c16 == 0 && l < LL) atomicAdd(&sbBuf[(size_t)pair * 120 + l * 4 + h], v);
          }
        }
    }
  }
}

// ---- finalize: head softmax, u-vectors, bilinears. grid 2304 ----
__global__ __launch_bounds__(256) void finalize_kernel(
    const float* __restrict__ Sb, const float* __restrict__ Cb,
    const float* __restrict__ g22, const float* __restrict__ g11,
    const float* __restrict__ saBuf, const float* __restrict__ sbBuf,
    float* __restrict__ out) {
  const int pair = blockIdx.x;
  const int a = pair / NB2;
  const int b = pair - a * NB2;
  const int t = threadIdx.x, w = t >> 6;

  __shared__ float sS[LL][RR];
  __shared__ float p1s[LL][RR];
  __shared__ float p2s[RR][32];
  __shared__ float sa[RR][NH];
  __shared__ float sbm[LL][NH];
  __shared__ float qa[RR], qb[LL], u1[RR], u2[LL];
  __shared__ float redbuf[3][4];

  for (int i = t; i < LL * RR; i += 256) {
    int l = i / RR, r = i - l * RR;
    sS[l][r] = Sb[(size_t)(b * LL + l) * 1728 + a * RR + r];
  }
  if (t < RR * NH) ((float*)sa)[t] = saBuf[(size_t)pair * 144 + t];
  if (t >= 128 && t < 128 + LL * NH) ((float*)sbm)[t - 128] = sbBuf[(size_t)pair * 120 + (t - 128)];
  __syncthreads();

  if (t < LL) {
    float m = -1e30f;
    for (int r = 0; r < RR; ++r) m = fmaxf(m, sS[t][r]);
    float s = 0.f;
    for (int r = 0; r < RR; ++r) { float e = __expf(sS[t][r] - m); p1s[t][r] = e; s += e; }
    float inv = 1.f / s;
    for (int r = 0; r < RR; ++r) p1s[t][r] *= inv;
  } else if (t >= 64 && t < 64 + RR) {
    int r = t - 64;
    float m = -1e30f;
    for (int l = 0; l < LL; ++l) m = fmaxf(m, sS[l][r]);
    float s = 0.f;
    for (int l = 0; l < LL; ++l) { float e = __expf(sS[l][r] - m); p2s[r][l] = e; s += e; }
    float inv = 1.f / s;
    for (int l = 0; l < LL; ++l) p2s[r][l] *= inv;
  } else if (t >= 128 && t < 128 + NH) {
    const int h = t - 128;
    float m = -1e30f;
    for (int r = 0; r < RR; ++r) m = fmaxf(m, sa[r][h]);
    float s = 0.f;
    for (int r = 0; r < RR; ++r) { float e = __expf(sa[r][h] - m); sa[r][h] = e; s += e; }
    float inv = 1.f / s;
    for (int r = 0; r < RR; ++r) sa[r][h] *= inv;
  } else if (t >= 192 && t < 192 + NH) {
    const int h = t - 192;
    float m = -1e30f;
    for (int l = 0; l < LL; ++l) m = fmaxf(m, sbm[l][h]);
    float s = 0.f;
    for (int l = 0; l < LL; ++l) { float e = __expf(sbm[l][h] - m); sbm[l][h] = e; s += e; }
    float inv = 1.f / s;
    for (int l = 0; l < LL; ++l) sbm[l][h] *= inv;
  }
  __syncthreads();
  if (t < RR) qa[t] = 0.25f * (sa[t][0] + sa[t][1] + sa[t][2] + sa[t][3]);
  else if (t >= 64 && t < 64 + LL) {
    int l = t - 64;
    qb[l] = 0.25f * (sbm[l][0] + sbm[l][1] + sbm[l][2] + sbm[l][3]);
  }
  __syncthreads();

  if (t < LL) {
    float x = 0.f;
    for (int r = 0; r < RR; ++r) x = fmaf(qa[r], p2s[r][t], x);
    u2[t] = x;
  } else if (t >= 64 && t < 64 + RR) {
    int r = t - 64;
    float x = 0.f;
    for (int l = 0; l < LL; ++l) x = fmaf(qb[l], p1s[l][r], x);
    u1[r] = x;
  }
  __syncthreads();

  float pnum = 0.f, pn1 = 0.f, pn2 = 0.f;
  {
    const float* Cab = Cb + (size_t)(b * LL) * 1728 + a * RR;
    for (int i = t; i < LL * RR; i += 256) {
      int l = i / RR, r = i - l * RR;
      pnum = fmaf(u2[l] * u1[r], Cab[(size_t)l * 1728 + r], pnum);
    }
    const float* G22 = g22 + (size_t)b * LL * LL;
    for (int i = t; i < LL * LL; i += 256) {
      int l = i / LL, l2 = i - l * LL;
      pn1 = fmaf(u2[l] * u2[l2], G22[i], pn1);
    }
    const float* G11 = g11 + (size_t)a * RR * RR;
    for (int i = t; i < RR * RR; i += 256) {
      int r = i / RR, r2 = i - r * RR;
      pn2 = fmaf(u1[r] * u1[r2], G11[i], pn2);
    }
  }
#pragma unroll
  for (int off = 32; off > 0; off >>= 1) {
    pnum += __shfl_down(pnum, off);
    pn1  += __shfl_down(pn1, off);
    pn2  += __shfl_down(pn2, off);
  }
  if ((t & 63) == 0) { redbuf[0][w] = pnum; redbuf[1][w] = pn1; redbuf[2][w] = pn2; }
  __syncthreads();
  if (t == 0) {
    float num = redbuf[0][0] + redbuf[0][1] + redbuf[0][2] + redbuf[0][3];
    float n1s = redbuf[1][0] + redbuf[1][1] + redbuf[1][2] + redbuf[1][3];
    float n2s = redbuf[2][0] + redbuf[2][1] + redbuf[2][2] + redbuf[2][3];
    float n1 = sqrtf(fmaxf(n1s, 0.f));
    float n2 = sqrtf(fmaxf(n2s, 0.f));
    out[pair] = num / ((n1 + 1e-8f) * (n2 + 1e-8f));
  }
}

extern "C" void kernel_launch(void* const* d_in, const int* in_sizes, int n_in,
                              void* d_out, int out_size, void* d_ws, size_t ws_size,
                              hipStream_t stream) {
  const float* v1    = (const float*)d_in[0];
  const float* v2    = (const float*)d_in[1];
  const float* w_img = (const float*)d_in[2];
  const float* w_txt = (const float*)d_in[3];
  const float* w1a   = (const float*)d_in[4];
  const float* b1a   = (const float*)d_in[5];
  const float* w2a   = (const float*)d_in[6];
  const float* w1b   = (const float*)d_in[8];
  const float* b1b   = (const float*)d_in[9];
  const float* w2b   = (const float*)d_in[10];
  float* out = (float*)d_out;

  float* ws   = (float*)d_ws;
  float* k1   = ws;
  float* k2   = k1 + (size_t)1728 * 1024;
  float* G2a  = k2 + (size_t)1440 * 1024;
  float* G1b  = G2a + (size_t)1440 * 1024;
  float* Sbuf = G1b + (size_t)1728 * 1024;
  float* Cbuf = Sbuf + (size_t)1440 * 1728;
  float* g22  = Cbuf + (size_t)1440 * 1728;
  float* g11  = g22 + (size_t)48 * 900;

  ush* fb    = (ush*)(g11 + (size_t)48 * 1296);
  ush* v1f   = fb;
  ush* v2f   = v1f + (size_t)108 * 32768;
  ush* k1f   = v2f + (size_t)92 * 32768;
  ush* k2f   = k1f + (size_t)108 * 32768;
  ush* wimgf = k2f + (size_t)92 * 32768;
  ush* wtxtf = wimgf + (size_t)64 * 32768;
  ush* w1af  = wtxtf + (size_t)64 * 32768;
  ush* w1bf  = w1af + (size_t)64 * 32768;
  ush* G2aF  = w1bf + (size_t)64 * 32768;
  ush* G1bF  = G2aF + (size_t)48 * 65536;
  float* saBuf = (float*)(G1bF + (size_t)48 * 131072);   // 2304*144
  float* sbBuf = saBuf + (size_t)2304 * 144;             // 2304*120

  float* pg = (float*)k1f;          // gram partials alias k1f (dead window)
  // p2F/p1F alias the frag region (v1f..w1bf dead after cross_fused):
  ush* p2F = v1f;                                   // 2304*3072 = 7,077,888 ush
  ush* p1F = v1f + (size_t)2304 * 3072;             // 2304*4096 = 9,437,184 ush (fits)

  hipMemsetAsync(saBuf, 0, (size_t)2304 * (144 + 120) * sizeof(float), stream);

  conv6<<<dim3(864, 6), 256, 0, stream>>>(v1, v2, w_img, w_txt, w1a, w1b,
                                          v1f, v2f, wimgf, wtxtf, w1af, w1bf);
  gram_partial<<<dim3(8, 96), 256, 0, stream>>>(v1, v2, pg);
  gram_reduce<<<96, 256, 0, stream>>>(pg, g11, g22);

  proj_fused<<<dim3(8, 14, 4), 256, 0, stream>>>(
      (const bf16x8*)v1f, (const bf16x8*)v2f, (const bf16x8*)wimgf,
      (const bf16x8*)wtxtf, (const bf16x8*)w1af, (const bf16x8*)w1bf,
      k1, k2, G2a, G1b);

  conv_post<<<3264, 256, 0, stream>>>(k1, k2, G2a, G1b, k1f, k2f, G2aF, G1bF);

  cross_fused<<<dim3(14, 12, 2), 256, 0, stream>>>(
      (const bf16x8*)k2f, (const bf16x8*)k1f, (const bf16x8*)v2f, (const bf16x8*)v1f,
      Sbuf, Cbuf);

  softmax_frag<<<2304, 256, 0, stream>>>(Sbuf, p2F, p1F);

  score_kernel<<<2304, 256, 0, stream>>>(
      (const bf16x8*)G2aF, (const bf16x8*)G1bF,
      (const bf16x8*)p2F, (const bf16x8*)p1F,
      b1a, w2a, b1b, w2b, saBuf, sbBuf);

  finalize_kernel<<<2304, 256, 0, stream>>>(Sbuf, Cbuf, g22, g11, saBuf, sbBuf, out);
}

// Round 9
// 380.784 us; speedup vs baseline: 1.3121x; 1.1214x over previous
//
#include <hip/hip_runtime.h>

#define D 1024
#define NB1 48
#define NB2 48
#define RR 36
#define LL 30
#define NH 4

typedef short bf16x8 __attribute__((ext_vector_type(8)));
typedef float f32x4 __attribute__((ext_vector_type(4)));
typedef unsigned short u16x8 __attribute__((ext_vector_type(8)));
typedef unsigned short ush;

#define MFMA16(a, b, c) __builtin_amdgcn_mfma_f32_16x16x32_bf16(a, b, c, 0, 0, 0)

__device__ __forceinline__ ush f2bf(float x) {
  unsigned u = __float_as_uint(x);
  u += 0x7FFF + ((u >> 16) & 1);
  return (ush)(u >> 16);
}
__device__ __forceinline__ float bf2f(ush h) {
  return __uint_as_float(((unsigned)h) << 16);
}
__device__ __forceinline__ void split8(const float* v, bf16x8& h8, bf16x8& l8) {
  u16x8 hi, lo;
#pragma unroll
  for (int i = 0; i < 8; ++i) {
    ush h = f2bf(v[i]);
    hi[i] = h;
    lo[i] = f2bf(v[i] - bf2f(h));
  }
  h8 = __builtin_bit_cast(bf16x8, hi);
  l8 = __builtin_bit_cast(bf16x8, lo);
}

// ---- fp32 row-major (rows x 1024) -> split-bf16 MFMA fragment layout ----
__device__ __forceinline__ void conv_body(const float* __restrict__ X,
                                          ush* __restrict__ out,
                                          int rows, int g) {
  const int lane = threadIdx.x & 63;
  const int tile = g >> 5, kc = g & 31;
  const int row = tile * 16 + (lane & 15);
  const int k = kc * 32 + (lane >> 4) * 8;
  float v[8];
  if (row < rows) {
    const float4* s = (const float4*)(X + (size_t)row * 1024 + k);
    float4 x0 = s[0], x1 = s[1];
    v[0] = x0.x; v[1] = x0.y; v[2] = x0.z; v[3] = x0.w;
    v[4] = x1.x; v[5] = x1.y; v[6] = x1.z; v[7] = x1.w;
  } else {
#pragma unroll
    for (int i = 0; i < 8; ++i) v[i] = 0.f;
  }
  bf16x8 hi, lo;
  split8(v, hi, lo);
  bf16x8* o = (bf16x8*)(out + (size_t)g * 1024 + lane * 8);
  o[0] = hi;
  o[64] = lo;
}

// 6 input matrices in one launch. grid (864, 6)
__global__ __launch_bounds__(256) void conv6(
    const float* __restrict__ v1, const float* __restrict__ v2,
    const float* __restrict__ wimg, const float* __restrict__ wtxt,
    const float* __restrict__ w1a, const float* __restrict__ w1b,
    ush* v1f, ush* v2f, ush* wimgf, ush* wtxtf, ush* w1af, ush* w1bf) {
  const float* X; ush* O; int rows;
  switch (blockIdx.y) {
    case 0: X = v1; O = v1f; rows = 1728; break;
    case 1: X = v2; O = v2f; rows = 1440; break;
    case 2: X = wimg; O = wimgf; rows = 1024; break;
    case 3: X = wtxt; O = wtxtf; rows = 1024; break;
    case 4: X = w1a; O = w1af; rows = 1024; break;
    default: X = w1b; O = w1bf; rows = 1024; break;
  }
  const int tiles = (rows + 15) >> 4;
  const int g = blockIdx.x * 4 + (threadIdx.x >> 6);
  if (g >= tiles * 32) return;
  conv_body(X, O, rows, g);
}

// merged: conv k1,k2 + convG. 1D grid 3264 blocks.
__global__ __launch_bounds__(256) void conv_post(
    const float* __restrict__ k1, const float* __restrict__ k2,
    const float* __restrict__ G2a, const float* __restrict__ G1b,
    ush* k1f, ush* k2f, ush* G2aF, ush* G1bF) {
  const int bid = blockIdx.x;
  const int t = threadIdx.x, lane = t & 63;
  if (bid < 1728) {
    const float* X = (bid >= 864) ? k2 : k1;
    ush* O = (bid >= 864) ? k2f : k1f;
    const int rows = (bid >= 864) ? 1440 : 1728;
    const int bx = (bid >= 864) ? bid - 864 : bid;
    const int tiles = (rows + 15) >> 4;
    const int g = bx * 4 + (t >> 6);
    if (g < tiles * 32) conv_body(X, O, rows, g);
  } else if (bid < 2496) {
    const int x = bid - 1728;
    const int bb = x >> 4;
    const int nt = ((x & 15) << 2) + (t >> 6);
    const int c = lane & 15, q = lane >> 4;
    float v[8];
#pragma unroll
    for (int j = 0; j < 8; ++j) {
      int l = q * 8 + j;
      v[j] = (l < LL) ? G2a[(size_t)(bb * LL + l) * D + nt * 16 + c] : 0.f;
    }
    bf16x8 hi, lo;
    split8(v, hi, lo);
    bf16x8* o = (bf16x8*)(G2aF + ((size_t)(bb * 64 + nt) * 2) * 512 + lane * 8);
    o[0] = hi;
    o[64] = lo;
  } else {
    const int x = bid - 2496;
    const int aa = x >> 4;
    const int nt = ((x & 15) << 2) + (t >> 6);
    const int c = lane & 15, q = lane >> 4;
#pragma unroll
    for (int kc = 0; kc < 2; ++kc) {
      float v[8];
#pragma unroll
      for (int j = 0; j < 8; ++j) {
        int r = kc * 32 + q * 8 + j;
        v[j] = (r < RR) ? G1b[(size_t)(aa * RR + r) * D + nt * 16 + c] : 0.f;
      }
      bf16x8 hi, lo;
      split8(v, hi, lo);
      bf16x8* o = (bf16x8*)(G1bF + (((size_t)(aa * 64 + nt) * 2 + kc) * 2) * 512 + lane * 8);
      o[0] = hi;
      o[64] = lo;
    }
  }
}

// ---- split-bf16 MFMA GEMM core ----
__device__ __forceinline__ void gemm4_body(const bf16x8* __restrict__ Af,
                                           const bf16x8* __restrict__ Bf,
                                           float* __restrict__ C,
                                           int M, int N, float scale,
                                           int Mtiles, int Ntiles) {
  const int lane = threadIdx.x & 63;
  const int w = threadIdx.x >> 6;
  const int mb = blockIdx.y * 8 + (w >> 1) * 4;
  const int nb = blockIdx.x * 8 + (w & 1) * 4;
  size_t ab[4], bb[4];
#pragma unroll
  for (int i = 0; i < 4; ++i) {
    int tm = mb + i; if (tm > Mtiles - 1) tm = Mtiles - 1;
    ab[i] = (size_t)tm * 4096 + lane;
    int tn = nb + i; if (tn > Ntiles - 1) tn = Ntiles - 1;
    bb[i] = (size_t)tn * 4096 + lane;
  }
  f32x4 acc[4][4];
#pragma unroll
  for (int i = 0; i < 4; ++i)
#pragma unroll
    for (int j = 0; j < 4; ++j) acc[i][j] = (f32x4){0.f, 0.f, 0.f, 0.f};
#pragma unroll 1
  for (int kc = 0; kc < 32; ++kc) {
    bf16x8 ah[4], al[4], bh[4], bl[4];
#pragma unroll
    for (int i = 0; i < 4; ++i) { ah[i] = Af[ab[i]]; al[i] = Af[ab[i] + 64]; ab[i] += 128; }
#pragma unroll
    for (int j = 0; j < 4; ++j) { bh[j] = Bf[bb[j]]; bl[j] = Bf[bb[j] + 64]; bb[j] += 128; }
#pragma unroll
    for (int i = 0; i < 4; ++i)
#pragma unroll
      for (int j = 0; j < 4; ++j) {
        acc[i][j] = MFMA16(ah[i], bh[j], acc[i][j]);
        acc[i][j] = MFMA16(al[i], bh[j], acc[i][j]);
        acc[i][j] = MFMA16(ah[i], bl[j], acc[i][j]);
      }
  }
  const int c16 = lane & 15, q = lane >> 4;
#pragma unroll
  for (int i = 0; i < 4; ++i) {
#pragma unroll
    for (int reg = 0; reg < 4; ++reg) {
      int r = (mb + i) * 16 + q * 4 + reg;
      if (r < M) {
#pragma unroll
        for (int j = 0; j < 4; ++j) {
          int col = (nb + j) * 16 + c16;
          if (col < N) C[(size_t)r * N + col] = acc[i][j][reg] * scale;
        }
      }
    }
  }
}

// 4 projection GEMMs in one launch. grid (8, 14, 4)
__global__ __launch_bounds__(256) void proj_fused(
    const bf16x8* __restrict__ v1f, const bf16x8* __restrict__ v2f,
    const bf16x8* __restrict__ wimgf, const bf16x8* __restrict__ wtxtf,
    const bf16x8* __restrict__ w1af, const bf16x8* __restrict__ w1bf,
    float* k1, float* k2, float* G2a, float* G1b) {
  const int z = blockIdx.z;
  const bf16x8* Af = (z == 0 || z == 3) ? v1f : v2f;
  const bf16x8* Bf = (z == 0) ? wimgf : (z == 1) ? wtxtf : (z == 2) ? w1af : w1bf;
  float* C = (z == 0) ? k1 : (z == 1) ? k2 : (z == 2) ? G2a : G1b;
  const int M = (z == 0 || z == 3) ? 1728 : 1440;
  const int Mt = (z == 0 || z == 3) ? 108 : 92;
  if ((int)blockIdx.y * 8 >= Mt) return;
  gemm4_body(Af, Bf, C, M, 1024, 1.f, Mt, 64);
}

// 2 cross GEMMs in one launch. grid (14, 12, 2)
__global__ __launch_bounds__(256) void cross_fused(
    const bf16x8* __restrict__ k2f, const bf16x8* __restrict__ k1f,
    const bf16x8* __restrict__ v2f, const bf16x8* __restrict__ v1f,
    float* Sbuf, float* Cbuf) {
  if (blockIdx.z == 0) gemm4_body(k2f, k1f, Sbuf, 1440, 1728, 0.03125f, 92, 108);
  else                 gemm4_body(v2f, v1f, Cbuf, 1440, 1728, 1.f, 92, 108);
}

// ---- Gram partials: grid (8, 96) ----
__global__ __launch_bounds__(256) void gram_partial(const float* __restrict__ v1,
                                                    const float* __restrict__ v2,
                                                    float* __restrict__ pg) {
  const int y = blockIdx.y, cx = blockIdx.x;
  const int isV1 = y < 48;
  const int batch = isV1 ? y : y - 48;
  const int Nr = isV1 ? RR : LL;
  const float* base = isV1 ? v1 + (size_t)batch * RR * D : v2 + (size_t)batch * LL * D;
  __shared__ __align__(16) float vs[36][132];
  const int t = threadIdx.x;
  for (int idx = t; idx < Nr * 32; idx += 256) {
    int row = idx >> 5, c4 = idx & 31;
    *(float4*)&vs[row][c4 * 4] = *(const float4*)&base[(size_t)row * D + cx * 128 + c4 * 4];
  }
  __syncthreads();
  const int nt3 = Nr / 3;
  float acc[3][3] = {{0.f,0.f,0.f},{0.f,0.f,0.f},{0.f,0.f,0.f}};
  const int i0 = (t / nt3) * 3, j0 = (t - (t / nt3) * nt3) * 3;
  if (t < nt3 * nt3) {
    for (int k4 = 0; k4 < 32; ++k4) {
      float4 a[3], b[3];
#pragma unroll
      for (int ii = 0; ii < 3; ++ii) a[ii] = *(const float4*)&vs[i0 + ii][k4 * 4];
#pragma unroll
      for (int jj = 0; jj < 3; ++jj) b[jj] = *(const float4*)&vs[j0 + jj][k4 * 4];
#pragma unroll
      for (int ii = 0; ii < 3; ++ii)
#pragma unroll
        for (int jj = 0; jj < 3; ++jj) {
          acc[ii][jj] = fmaf(a[ii].x, b[jj].x, acc[ii][jj]);
          acc[ii][jj] = fmaf(a[ii].y, b[jj].y, acc[ii][jj]);
          acc[ii][jj] = fmaf(a[ii].z, b[jj].z, acc[ii][jj]);
          acc[ii][jj] = fmaf(a[ii].w, b[jj].w, acc[ii][jj]);
        }
    }
    float* o = pg + ((size_t)y * 8 + cx) * 1296;
#pragma unroll
    for (int ii = 0; ii < 3; ++ii)
#pragma unroll
      for (int jj = 0; jj < 3; ++jj) o[(i0 + ii) * Nr + (j0 + jj)] = acc[ii][jj];
  }
}

__global__ __launch_bounds__(256) void gram_reduce(const float* __restrict__ pg,
                                                   float* __restrict__ g11,
                                                   float* __restrict__ g22) {
  const int y = blockIdx.x;
  const int isV1 = y < 48;
  const int batch = isV1 ? y : y - 48;
  const int NN = isV1 ? RR * RR : LL * LL;
  const float* p = pg + (size_t)y * 8 * 1296;
  float* o = isV1 ? g11 + (size_t)batch * RR * RR : g22 + (size_t)batch * LL * LL;
  for (int i = threadIdx.x; i < NN; i += 256) {
    float s = 0.f;
#pragma unroll
    for (int c = 0; c < 8; ++c) s += p[c * 1296 + i];
    o[i] = s;
  }
}

// ---- softmax + SPLIT-bf16 A-fragment precompute: grid 2304 ----
__global__ __launch_bounds__(256) void softmax_frag(const float* __restrict__ Sb,
                                                    ush* __restrict__ p2F,
                                                    ush* __restrict__ p1F) {
  const int pair = blockIdx.x;
  const int a = pair / NB2;
  const int b = pair - a * NB2;
  const int t = threadIdx.x, lane = t & 63;
  __shared__ __align__(16) float sS[LL][RR];
  __shared__ __align__(16) float p2s[48][36];
  __shared__ __align__(16) float p1s[32][68];
  for (int i = t; i < 48 * 36; i += 256) ((float*)p2s)[i] = 0.f;
  for (int i = t; i < 32 * 68; i += 256) ((float*)p1s)[i] = 0.f;
  for (int i = t; i < LL * RR; i += 256) {
    int l = i / RR, r = i - l * RR;
    sS[l][r] = Sb[(size_t)(b * LL + l) * 1728 + a * RR + r];
  }
  __syncthreads();
  if (t < LL) {
    float m = -1e30f;
    for (int r = 0; r < RR; ++r) m = fmaxf(m, sS[t][r]);
    float s = 0.f;
    for (int r = 0; r < RR; ++r) { float e = __expf(sS[t][r] - m); p1s[t][r] = e; s += e; }
    float inv = 1.f / s;
    for (int r = 0; r < RR; ++r) p1s[t][r] *= inv;
  } else if (t >= 64 && t < 64 + RR) {
    int r = t - 64;
    float m = -1e30f;
    for (int l = 0; l < LL; ++l) m = fmaxf(m, sS[l][r]);
    float s = 0.f;
    for (int l = 0; l < LL; ++l) { float e = __expf(sS[l][r] - m); p2s[r][l] = e; s += e; }
    float inv = 1.f / s;
    for (int l = 0; l < LL; ++l) p2s[r][l] *= inv;
  }
  __syncthreads();
  const int mr = lane & 15, q = lane >> 4;
  if (t < 192) {
    const int mt = t >> 6;
    float v[8];
#pragma unroll
    for (int j = 0; j < 8; ++j) v[j] = p2s[mt * 16 + mr][q * 8 + j];
    bf16x8 hi, lo;
    split8(v, hi, lo);
    bf16x8* o = (bf16x8*)p2F + (size_t)(pair * 3 + mt) * 128 + lane;
    o[0] = hi;
    o[64] = lo;
  }
  {
    const int mt = t >> 7, kc = (t >> 6) & 1;
    float v[8];
#pragma unroll
    for (int j = 0; j < 8; ++j) v[j] = p1s[mt * 16 + mr][kc * 32 + q * 8 + j];
    bf16x8 hi, lo;
    split8(v, hi, lo);
    bf16x8* o = (bf16x8*)p1F + (size_t)(pair * 2 + mt) * 256 + kc * 128 + lane;
    o[0] = hi;
    o[64] = lo;
  }
}

// ---- score v4: grid 768 = 384 dirA (b*8+eg) + 384 dirB (a*8+eg) ----
__global__ __launch_bounds__(256) void score_kernel(
    const bf16x8* __restrict__ G2aF, const bf16x8* __restrict__ G1bF,
    const bf16x8* __restrict__ p2F, const bf16x8* __restrict__ p1F,
    const float* __restrict__ b1a, const float* __restrict__ w2a,
    const float* __restrict__ b1b, const float* __restrict__ w2b,
    float* __restrict__ saP, float* __restrict__ sbP) {
  __shared__ __align__(16) ush gstage[16384];     // 32 KB (dirA uses 16 KB)
  __shared__ float wbs[640];                      // bias + 4 w2 rows, 128 cols
  const int t = threadIdx.x, lane = t & 63, w = t >> 6;
  const int c16 = lane & 15, q = lane >> 4;
  const int bid = blockIdx.x;

  if (bid < 384) {
    const int b = bid >> 3, eg = bid & 7;
    {
      const bf16x8* src = G2aF + (size_t)(b * 64 + eg * 8) * 128;
      bf16x8* dst = (bf16x8*)gstage;
      for (int i = t; i < 1024; i += 256) dst[i] = src[i];
    }
    if (t < 128) {
      const int col = eg * 128 + t;
      wbs[t] = b1a[col];
      wbs[128 + t] = w2a[col];
      wbs[256 + t] = w2a[1024 + col];
      wbs[384 + t] = w2a[2048 + col];
      wbs[512 + t] = w2a[3072 + col];
    }
    __syncthreads();
    const bf16x8* gs = (const bf16x8*)gstage;
#pragma unroll 1
    for (int i = 0; i < 12; ++i) {
      const int a = w * 12 + i;
      const int pair = a * 48 + b;
      bf16x8 Ah[3], Al[3];
#pragma unroll
      for (int mt = 0; mt < 3; ++mt) {
        const bf16x8* pp = p2F + (size_t)(pair * 3 + mt) * 128 + lane;
        Ah[mt] = pp[0];
        Al[mt] = pp[64];
      }
      float scP[3][4][NH];
#pragma unroll
      for (int mt = 0; mt < 3; ++mt)
#pragma unroll
        for (int reg = 0; reg < 4; ++reg)
#pragma unroll
          for (int h = 0; h < NH; ++h) scP[mt][reg][h] = 0.f;
#pragma unroll 2
      for (int ntL = 0; ntL < 8; ++ntL) {
        bf16x8 Bh = gs[ntL * 128 + lane], Bl = gs[ntL * 128 + 64 + lane];
        const int cc = ntL * 16 + c16;
        const float bias = wbs[cc];
        const float w0 = wbs[128 + cc], w1 = wbs[256 + cc];
        const float w2v = wbs[384 + cc], w3 = wbs[512 + cc];
#pragma unroll
        for (int mt = 0; mt < 3; ++mt) {
          f32x4 acc = {bias, bias, bias, bias};
          acc = MFMA16(Ah[mt], Bh, acc);
          acc = MFMA16(Al[mt], Bh, acc);
          acc = MFMA16(Ah[mt], Bl, acc);
#pragma unroll
          for (int reg = 0; reg < 4; ++reg) {
            float hv = fmaxf(acc[reg], 0.f);
            scP[mt][reg][0] = fmaf(hv, w0, scP[mt][reg][0]);
            scP[mt][reg][1] = fmaf(hv, w1, scP[mt][reg][1]);
            scP[mt][reg][2] = fmaf(hv, w2v, scP[mt][reg][2]);
            scP[mt][reg][3] = fmaf(hv, w3, scP[mt][reg][3]);
          }
        }
      }
      float* o = saP + ((size_t)eg * 2304 + pair) * 144;
#pragma unroll
      for (int mt = 0; mt < 3; ++mt)
#pragma unroll
        for (int reg = 0; reg < 4; ++reg) {
          const int r = mt * 16 + q * 4 + reg;
#pragma unroll
          for (int h = 0; h < NH; ++h) {
            float v = scP[mt][reg][h];
            v += __shfl_xor(v, 1); v += __shfl_xor(v, 2);
            v += __shfl_xor(v, 4); v += __shfl_xor(v, 8);
            scP[mt][reg][h] = v;
          }
          if (c16 < 4 && r < RR) o[r * 4 + c16] = scP[mt][reg][c16];
        }
    }
  } else {
    const int bid2 = bid - 384;
    const int a = bid2 >> 3, eg = bid2 & 7;
    {
      const bf16x8* src = G1bF + (size_t)(a * 64 + eg * 8) * 256;
      bf16x8* dst = (bf16x8*)gstage;
      for (int i = t; i < 2048; i += 256) dst[i] = src[i];
    }
    if (t < 128) {
      const int col = eg * 128 + t;
      wbs[t] = b1b[col];
      wbs[128 + t] = w2b[col];
      wbs[256 + t] = w2b[1024 + col];
      wbs[384 + t] = w2b[2048 + col];
      wbs[512 + t] = w2b[3072 + col];
    }
    __syncthreads();
    const bf16x8* gs = (const bf16x8*)gstage;
#pragma unroll 1
    for (int i = 0; i < 12; ++i) {
      const int b = w * 12 + i;
      const int pair = a * 48 + b;
      bf16x8 Ah[2][2], Al[2][2];
#pragma unroll
      for (int mt = 0; mt < 2; ++mt)
#pragma unroll
        for (int kc = 0; kc < 2; ++kc) {
          const bf16x8* pp = p1F + (size_t)(pair * 2 + mt) * 256 + kc * 128 + lane;
          Ah[mt][kc] = pp[0];
          Al[mt][kc] = pp[64];
        }
      float scP[2][4][NH];
#pragma unroll
      for (int mt = 0; mt < 2; ++mt)
#pragma unroll
        for (int reg = 0; reg < 4; ++reg)
#pragma unroll
          for (int h = 0; h < NH; ++h) scP[mt][reg][h] = 0.f;
#pragma unroll 2
      for (int ntL = 0; ntL < 8; ++ntL) {
        bf16x8 B0h = gs[ntL * 256 + lane], B0l = gs[ntL * 256 + 64 + lane];
        bf16x8 B1h = gs[ntL * 256 + 128 + lane], B1l = gs[ntL * 256 + 192 + lane];
        const int cc = ntL * 16 + c16;
        const float bias = wbs[cc];
        const float w0 = wbs[128 + cc], w1 = wbs[256 + cc];
        const float w2v = wbs[384 + cc], w3 = wbs[512 + cc];
#pragma unroll
        for (int mt = 0; mt < 2; ++mt) {
          f32x4 acc = {bias, bias, bias, bias};
          acc = MFMA16(Ah[mt][0], B0h, acc);
          acc = MFMA16(Al[mt][0], B0h, acc);
          acc = MFMA16(Ah[mt][0], B0l, acc);
          acc = MFMA16(Ah[mt][1], B1h, acc);
          acc = MFMA16(Al[mt][1], B1h, acc);
          acc = MFMA16(Ah[mt][1], B1l, acc);
#pragma unroll
          for (int reg = 0; reg < 4; ++reg) {
            float hv = fmaxf(acc[reg], 0.f);
            scP[mt][reg][0] = fmaf(hv, w0, scP[mt][reg][0]);
            scP[mt][reg][1] = fmaf(hv, w1, scP[mt][reg][1]);
            scP[mt][reg][2] = fmaf(hv, w2v, scP[mt][reg][2]);
            scP[mt][reg][3] = fmaf(hv, w3, scP[mt][reg][3]);
          }
        }
      }
      float* o = sbP + ((size_t)eg * 2304 + pair) * 120;
#pragma unroll
      for (int mt = 0; mt < 2; ++mt)
#pragma unroll
        for (int reg = 0; reg < 4; ++reg) {
          const int l = mt * 16 + q * 4 + reg;
#pragma unroll
          for (int h = 0; h < NH; ++h) {
            float v = scP[mt][reg][h];
            v += __shfl_xor(v, 1); v += __shfl_xor(v, 2);
            v += __shfl_xor(v, 4); v += __shfl_xor(v, 8);
            scP[mt][reg][h] = v;
          }
          if (c16 < 4 && l < LL) o[l * 4 + c16] = scP[mt][reg][c16];
        }
    }
  }
}

// ---- finalize: sum 8 partials, head softmax, u-vectors, bilinears. grid 2304 ----
__global__ __launch_bounds__(256) void finalize_kernel(
    const float* __restrict__ Sb, const float* __restrict__ Cb,
    const float* __restrict__ g22, const float* __restrict__ g11,
    const float* __restrict__ saP, const float* __restrict__ sbP,
    float* __restrict__ out) {
  const int pair = blockIdx.x;
  const int a = pair / NB2;
  const int b = pair - a * NB2;
  const int t = threadIdx.x, w = t >> 6;

  __shared__ float sS[LL][RR];
  __shared__ float p1s[LL][RR];
  __shared__ float p2s[RR][32];
  __shared__ float sa[RR][NH];
  __shared__ float sbm[LL][NH];
  __shared__ float qa[RR], qb[LL], u1[RR], u2[LL];
  __shared__ float redbuf[3][4];

  for (int i = t; i < LL * RR; i += 256) {
    int l = i / RR, r = i - l * RR;
    sS[l][r] = Sb[(size_t)(b * LL + l) * 1728 + a * RR + r];
  }
  // FIX (round 8 bug): two independent ifs so ALL 120 sbm entries are loaded.
  if (t < 144) {
    float s = 0.f;
#pragma unroll
    for (int eg = 0; eg < 8; ++eg) s += saP[((size_t)eg * 2304 + pair) * 144 + t];
    ((float*)sa)[t] = s;
  }
  if (t >= 128 && t < 128 + 120) {
    float s = 0.f;
#pragma unroll
    for (int eg = 0; eg < 8; ++eg) s += sbP[((size_t)eg * 2304 + pair) * 120 + (t - 128)];
    ((float*)sbm)[t - 128] = s;
  }
  __syncthreads();

  if (t < LL) {
    float m = -1e30f;
    for (int r = 0; r < RR; ++r) m = fmaxf(m, sS[t][r]);
    float s = 0.f;
    for (int r = 0; r < RR; ++r) { float e = __expf(sS[t][r] - m); p1s[t][r] = e; s += e; }
    float inv = 1.f / s;
    for (int r = 0; r < RR; ++r) p1s[t][r] *= inv;
  } else if (t >= 64 && t < 64 + RR) {
    int r = t - 64;
    float m = -1e30f;
    for (int l = 0; l < LL; ++l) m = fmaxf(m, sS[l][r]);
    float s = 0.f;
    for (int l = 0; l < LL; ++l) { float e = __expf(sS[l][r] - m); p2s[r][l] = e; s += e; }
    float inv = 1.f / s;
    for (int l = 0; l < LL; ++l) p2s[r][l] *= inv;
  } else if (t >= 128 && t < 128 + NH) {
    const int h = t - 128;
    float m = -1e30f;
    for (int r = 0; r < RR; ++r) m = fmaxf(m, sa[r][h]);
    float s = 0.f;
    for (int r = 0; r < RR; ++r) { float e = __expf(sa[r][h] - m); sa[r][h] = e; s += e; }
    float inv = 1.f / s;
    for (int r = 0; r < RR; ++r) sa[r][h] *= inv;
  } else if (t >= 192 && t < 192 + NH) {
    const int h = t - 192;
    float m = -1e30f;
    for (int l = 0; l < LL; ++l) m = fmaxf(m, sbm[l][h]);
    float s = 0.f;
    for (int l = 0; l < LL; ++l) { float e = __expf(sbm[l][h] - m); sbm[l][h] = e; s += e; }
    float inv = 1.f / s;
    for (int l = 0; l < LL; ++l) sbm[l][h] *= inv;
  }
  __syncthreads();
  if (t < RR) qa[t] = 0.25f * (sa[t][0] + sa[t][1] + sa[t][2] + sa[t][3]);
  else if (t >= 64 && t < 64 + LL) {
    int l = t - 64;
    qb[l] = 0.25f * (sbm[l][0] + sbm[l][1] + sbm[l][2] + sbm[l][3]);
  }
  __syncthreads();

  if (t < LL) {
    float x = 0.f;
    for (int r = 0; r < RR; ++r) x = fmaf(qa[r], p2s[r][t], x);
    u2[t] = x;
  } else if (t >= 64 && t < 64 + RR) {
    int r = t - 64;
    float x = 0.f;
    for (int l = 0; l < LL; ++l) x = fmaf(qb[l], p1s[l][r], x);
    u1[r] = x;
  }
  __syncthreads();

  float pnum = 0.f, pn1 = 0.f, pn2 = 0.f;
  {
    const float* Cab = Cb + (size_t)(b * LL) * 1728 + a * RR;
    for (int i = t; i < LL * RR; i += 256) {
      int l = i / RR, r = i - l * RR;
      pnum = fmaf(u2[l] * u1[r], Cab[(size_t)l * 1728 + r], pnum);
    }
    const float* G22 = g22 + (size_t)b * LL * LL;
    for (int i = t; i < LL * LL; i += 256) {
      int l = i / LL, l2 = i - l * LL;
      pn1 = fmaf(u2[l] * u2[l2], G22[i], pn1);
    }
    const float* G11 = g11 + (size_t)a * RR * RR;
    for (int i = t; i < RR * RR; i += 256) {
      int r = i / RR, r2 = i - r * RR;
      pn2 = fmaf(u1[r] * u1[r2], G11[i], pn2);
    }
  }
#pragma unroll
  for (int off = 32; off > 0; off >>= 1) {
    pnum += __shfl_down(pnum, off);
    pn1  += __shfl_down(pn1, off);
    pn2  += __shfl_down(pn2, off);
  }
  if ((t & 63) == 0) { redbuf[0][w] = pnum; redbuf[1][w] = pn1; redbuf[2][w] = pn2; }
  __syncthreads();
  if (t == 0) {
    float num = redbuf[0][0] + redbuf[0][1] + redbuf[0][2] + redbuf[0][3];
    float n1s = redbuf[1][0] + redbuf[1][1] + redbuf[1][2] + redbuf[1][3];
    float n2s = redbuf[2][0] + redbuf[2][1] + redbuf[2][2] + redbuf[2][3];
    float n1 = sqrtf(fmaxf(n1s, 0.f));
    float n2 = sqrtf(fmaxf(n2s, 0.f));
    out[pair] = num / ((n1 + 1e-8f) * (n2 + 1e-8f));
  }
}

extern "C" void kernel_launch(void* const* d_in, const int* in_sizes, int n_in,
                              void* d_out, int out_size, void* d_ws, size_t ws_size,
                              hipStream_t stream) {
  const float* v1    = (const float*)d_in[0];
  const float* v2    = (const float*)d_in[1];
  const float* w_img = (const float*)d_in[2];
  const float* w_txt = (const float*)d_in[3];
  const float* w1a   = (const float*)d_in[4];
  const float* b1a   = (const float*)d_in[5];
  const float* w2a   = (const float*)d_in[6];
  const float* w1b   = (const float*)d_in[8];
  const float* b1b   = (const float*)d_in[9];
  const float* w2b   = (const float*)d_in[10];
  float* out = (float*)d_out;

  float* ws   = (float*)d_ws;
  float* k1   = ws;
  float* k2   = k1 + (size_t)1728 * 1024;
  float* G2a  = k2 + (size_t)1440 * 1024;
  float* G1b  = G2a + (size_t)1440 * 1024;
  float* Sbuf = G1b + (size_t)1728 * 1024;
  float* Cbuf = Sbuf + (size_t)1440 * 1728;
  float* g22  = Cbuf + (size_t)1440 * 1728;
  float* g11  = g22 + (size_t)48 * 900;

  ush* fb    = (ush*)(g11 + (size_t)48 * 1296);
  ush* v1f   = fb;
  ush* v2f   = v1f + (size_t)108 * 32768;
  ush* k1f   = v2f + (size_t)92 * 32768;
  ush* k2f   = k1f + (size_t)108 * 32768;
  ush* wimgf = k2f + (size_t)92 * 32768;
  ush* wtxtf = wimgf + (size_t)64 * 32768;
  ush* w1af  = wtxtf + (size_t)64 * 32768;
  ush* w1bf  = w1af + (size_t)64 * 32768;
  ush* G2aF  = w1bf + (size_t)64 * 32768;
  ush* G1bF  = G2aF + (size_t)48 * 65536;

  float* pg = (float*)k1f;      // gram partials alias k1f (dead window pre conv_post)
  // p2F/p1F alias the whole v1f..w1bf span (all dead after cross_fused):
  ush* p2F = v1f;                                  // 2304*3072 ush = 14.2 MB
  ush* p1F = v1f + (size_t)2304 * 3072;            // 2304*4096 ush = 18.9 MB (33 < 43 MB span)
  // score partials alias fp32 k1..k2 and G2a..G1b (dead after conv_post):
  float* saP = k1;                                 // 8*2304*144 = 10.6 MB
  float* sbP = G2a;                                // 8*2304*120 = 8.8 MB

  conv6<<<dim3(864, 6), 256, 0, stream>>>(v1, v2, w_img, w_txt, w1a, w1b,
                                          v1f, v2f, wimgf, wtxtf, w1af, w1bf);
  gram_partial<<<dim3(8, 96), 256, 0, stream>>>(v1, v2, pg);
  gram_reduce<<<96, 256, 0, stream>>>(pg, g11, g22);

  proj_fused<<<dim3(8, 14, 4), 256, 0, stream>>>(
      (const bf16x8*)v1f, (const bf16x8*)v2f, (const bf16x8*)wimgf,
      (const bf16x8*)wtxtf, (const bf16x8*)w1af, (const bf16x8*)w1bf,
      k1, k2, G2a, G1b);

  conv_post<<<3264, 256, 0, stream>>>(k1, k2, G2a, G1b, k1f, k2f, G2aF, G1bF);

  cross_fused<<<dim3(14, 12, 2), 256, 0, stream>>>(
      (const bf16x8*)k2f, (const bf16x8*)k1f, (const bf16x8*)v2f, (const bf16x8*)v1f,
      Sbuf, Cbuf);

  softmax_frag<<<2304, 256, 0, stream>>>(Sbuf, p2F, p1F);

  score_kernel<<<768, 256, 0, stream>>>(
      (const bf16x8*)G2aF, (const bf16x8*)G1bF,
      (const bf16x8*)p2F, (const bf16x8*)p1F,
      b1a, w2a, b1b, w2b, saP, sbP);

  finalize_kernel<<<2304, 256, 0, stream>>>(Sbuf, Cbuf, g22, g11, saP, sbP, out);
}